// Round 10
// baseline (4147.556 us; speedup 1.0000x reference)
//
#include <hip/hip_runtime.h>
#include <stdint.h>

#define NN 100000
#define NE 3200000
#define NBK 782          // buckets of 128 dst nodes
#define NB  256          // sort blocks
#define CH  12500        // edges per sort block: 256*12500 = NE
#define SCAP 4608        // sort staging (mean 4092, +8 sigma)
#define PADW (128u << 17)

typedef unsigned int uint;
typedef unsigned short ushort;
typedef __attribute__((ext_vector_type(8))) short bf16x8;
typedef __attribute__((ext_vector_type(4))) float f32x4;

static __device__ __forceinline__ float bflo(uint v) {
    uint u = v << 16; return __builtin_bit_cast(float, u);
}
static __device__ __forceinline__ float bfhi(uint v) {
    uint u = v & 0xffff0000u; return __builtin_bit_cast(float, u);
}
static __device__ __forceinline__ float bfraw(uint v) {   // hi bf16 + low-bit junk (<=2^-9 rel)
    return __builtin_bit_cast(float, v);
}
static __device__ __forceinline__ ushort f2b(float f) {  // RNE fp32->bf16
    uint u = __builtin_bit_cast(uint, f);
    u += 0x7fffu + ((u >> 16) & 1u);
    return (ushort)(u >> 16);
}
static __device__ __forceinline__ int wscan(int v, int lane) {  // 64-lane inclusive
#pragma unroll
    for (int off = 1; off < 64; off <<= 1) {
        int t = __shfl_up(v, off);
        if (lane >= off) v += t;
    }
    return v;
}

// ---------------- bucket build ----------------

__global__ __launch_bounds__(512) void hist2_k(const int* __restrict__ ei,
                                               int* __restrict__ hist) {
    __shared__ int hl[NBK];
    int tid = threadIdx.x, b = blockIdx.x;
    for (int k = tid; k < NBK; k += 512) hl[k] = 0;
    __syncthreads();
    int base = b * CH;
    for (int i = base + tid; i < base + CH; i += 512)
        atomicAdd(&hl[ei[NE + i] >> 7], 1);
    __syncthreads();
    for (int k = tid; k < NBK; k += 512) hist[b * NBK + k] = hl[k];
}

__global__ __launch_bounds__(64) void pbase_k(const int* __restrict__ hist,
                                              int* __restrict__ pbase,
                                              int* __restrict__ totals) {
    int k = blockIdx.x, lane = threadIdx.x;
    int carry = 0;
#pragma unroll
    for (int c = 0; c < NB / 64; ++c) {
        int b = c * 64 + lane;
        int v = hist[b * NBK + k];
        int incl = wscan(v, lane);
        pbase[b * NBK + k] = carry + incl - v;
        carry += __shfl(incl, 63);
    }
    if (lane == 0) totals[k] = carry;
}

__global__ __launch_bounds__(1024) void bscan_k(const int* __restrict__ totals,
                                                int* __restrict__ gbase,
                                                ushort* __restrict__ y1a,
                                                ushort* __restrict__ y1b,
                                                ushort* __restrict__ y2) {
    __shared__ int sd[1024];
    int t = threadIdx.x;
    int v = (t < NBK) ? totals[t] : 0;
    sd[t] = v;
    __syncthreads();
    for (int off = 1; off < 1024; off <<= 1) {
        int u = (t >= off) ? sd[t - off] : 0;
        __syncthreads();
        sd[t] += u;
        __syncthreads();
    }
    int excl = sd[t] - v;
    if (t < NBK) gbase[t] = excl;
    if (t == 0) gbase[NBK] = NE;
    if (t < 32)              ((uint*)(y1a + (size_t)NN * 64))[t] = 0;
    else if (t < 64)         ((uint*)(y1b + (size_t)NN * 64))[t - 32] = 0;
    else if (t < 96)         ((uint*)(y2  + (size_t)NN * 64))[t - 64] = 0;
}

__global__ __launch_bounds__(512) void bfill2_k(const int* __restrict__ ei,
                                                const int* __restrict__ pbase,
                                                const int* __restrict__ gbase,
                                                uint* __restrict__ barr) {
    __shared__ int cur[NBK];
    int tid = threadIdx.x, b = blockIdx.x;
    for (int k = tid; k < NBK; k += 512)
        cur[k] = gbase[k] + pbase[b * NBK + k];
    __syncthreads();
    int base = b * CH;
    for (int i = base + tid; i < base + CH; i += 512) {
        int s = ei[i], d = ei[NE + i];
        int pos = atomicAdd(&cur[d >> 7], 1);       // LDS atomic only
        barr[pos] = ((uint)(d & 127) << 17) | (uint)s;
    }
}

// within-bucket counting sort by COARSE SRC (src>>9, 196 bins) -> barr2.
// All agg blocks then sweep y in the same order -> L2-resident moving window.
__global__ __launch_bounds__(256) void sort_k(const uint* __restrict__ barr,
                                              const int* __restrict__ gbase,
                                              uint* __restrict__ barr2) {
    __shared__ uint stg[SCAP];
    __shared__ int cnt[256], cur[256];
    int tid = threadIdx.x;
    int blk = blockIdx.x;
    int s0 = gbase[blk], s1 = gbase[blk + 1];
    int n = s1 - s0;
    bool fits = (n <= SCAP);
    cnt[tid] = 0;
    __syncthreads();
    if (fits) {
        for (int i = tid; i < n; i += 256) {
            uint e = barr[s0 + i];
            stg[i] = e;
            atomicAdd(&cnt[(e & 0x1FFFF) >> 9], 1);
        }
    } else {
        for (int i = s0 + tid; i < s1; i += 256)
            atomicAdd(&cnt[(barr[i] & 0x1FFFF) >> 9], 1);
    }
    __syncthreads();
    if (tid < 64) {
        int carry = 0;
#pragma unroll
        for (int c = 0; c < 4; ++c) {
            int k = c * 64 + tid;
            int v = cnt[k];
            int incl = wscan(v, tid);
            cur[k] = carry + incl - v;
            carry += __shfl(incl, 63);
        }
    }
    __syncthreads();
    if (fits) {
        for (int i = tid; i < n; i += 256) {
            uint e = stg[i];
            int pos = s0 + atomicAdd(&cur[(e & 0x1FFFF) >> 9], 1);
            barr2[pos] = e;
        }
    } else {
        for (int i = s0 + tid; i < s1; i += 256) {
            uint e = barr[i];
            int pos = s0 + atomicAdd(&cur[(e & 0x1FFFF) >> 9], 1);
            barr2[pos] = e;
        }
    }
}

// ---------------- GEMM1: y1 = bf16( x @ W1^T ), planar halves ----------------
__global__ __launch_bounds__(256) void gemm1_k(const float* __restrict__ x,
                                               const float* __restrict__ W1,
                                               ushort* __restrict__ y1a,
                                               ushort* __restrict__ y1b) {
    __shared__ ushort wl[128 * 136];
    int tid = threadIdx.x;
    for (int i = tid; i < 128 * 128; i += 256)
        wl[(i >> 7) * 136 + (i & 127)] = f2b(W1[i]);
    __syncthreads();

    int wave = tid >> 6, lane = tid & 63;
    int lr = lane & 15, lk = (lane >> 4) * 8;
    long rowbase = (long)blockIdx.x * 128 + wave * 32;

    f32x4 acc[2][8] = {};
    for (int kc = 0; kc < 128; kc += 32) {
        bf16x8 a[2];
#pragma unroll
        for (int m = 0; m < 2; m++) {
            long row = rowbase + m * 16 + lr;
            if (row > NN - 1) row = NN - 1;
            const float* p = x + row * 128 + kc + lk;
            float f[8];
            *(float4*)(f)     = *(const float4*)(p);
            *(float4*)(f + 4) = *(const float4*)(p + 4);
            bf16x8 t;
#pragma unroll
            for (int j = 0; j < 8; j++) t[j] = (short)f2b(f[j]);
            a[m] = t;
        }
#pragma unroll
        for (int nb = 0; nb < 8; nb++) {
            bf16x8 b = *(const bf16x8*)&wl[(nb * 16 + lr) * 136 + kc + lk];
            acc[0][nb] = __builtin_amdgcn_mfma_f32_16x16x32_bf16(a[0], b, acc[0][nb], 0, 0, 0);
            acc[1][nb] = __builtin_amdgcn_mfma_f32_16x16x32_bf16(a[1], b, acc[1][nb], 0, 0, 0);
        }
    }
    int rq = (lane >> 4) * 4;
#pragma unroll
    for (int m = 0; m < 2; m++) {
#pragma unroll
        for (int r = 0; r < 4; r++) {
            long row = rowbase + m * 16 + rq + r;
            if (row < NN) {
#pragma unroll
                for (int nb = 0; nb < 8; nb++) {
                    ushort v = f2b(acc[m][nb][r]);
                    if (nb < 4) y1a[row * 64 + nb * 16 + lr] = v;
                    else        y1b[row * 64 + (nb - 4) * 16 + lr] = v;
                }
            }
        }
    }
}

// ---------------- GEMM2: y2 = bf16( h @ W2^T ), h in planar halves ----------------
__global__ __launch_bounds__(256) void gemm2_k(const ushort* __restrict__ ha,
                                               const ushort* __restrict__ hb,
                                               const float* __restrict__ W2,
                                               ushort* __restrict__ y2) {
    __shared__ ushort wl[64 * 136];
    int tid = threadIdx.x;
    for (int i = tid; i < 64 * 128; i += 256)
        wl[(i >> 7) * 136 + (i & 127)] = f2b(W2[i]);
    __syncthreads();

    int wave = tid >> 6, lane = tid & 63;
    int lr = lane & 15, lk = (lane >> 4) * 8;
    long rowbase = (long)blockIdx.x * 128 + wave * 32;

    f32x4 acc[2][4] = {};
#pragma unroll
    for (int kc = 0; kc < 128; kc += 32) {
        const ushort* hsrc = (kc < 64) ? ha : hb;
        int koff = kc & 63;
        bf16x8 a[2];
#pragma unroll
        for (int m = 0; m < 2; m++) {
            long row = rowbase + m * 16 + lr;
            if (row > NN - 1) row = NN - 1;
            a[m] = *(const bf16x8*)(hsrc + row * 64 + koff + lk);
        }
#pragma unroll
        for (int nb = 0; nb < 4; nb++) {
            bf16x8 b = *(const bf16x8*)&wl[(nb * 16 + lr) * 136 + kc + lk];
            acc[0][nb] = __builtin_amdgcn_mfma_f32_16x16x32_bf16(a[0], b, acc[0][nb], 0, 0, 0);
            acc[1][nb] = __builtin_amdgcn_mfma_f32_16x16x32_bf16(a[1], b, acc[1][nb], 0, 0, 0);
        }
    }
    int rq = (lane >> 4) * 4;
#pragma unroll
    for (int m = 0; m < 2; m++) {
#pragma unroll
        for (int r = 0; r < 4; r++) {
            long row = rowbase + m * 16 + rq + r;
            if (row < NN) {
#pragma unroll
                for (int nb = 0; nb < 4; nb++)
                    y2[row * 64 + nb * 16 + lr] = f2b(acc[m][nb][r]);
            }
        }
    }
}

// ---------------- bucket-block LDS-scatter aggregation ----------------
// One 256-thr block per 128-node bucket; edges pre-sorted by coarse src.
// acc[129][65] fp32: +65 stride => bank (node+dim)%32, <=2-way in-oct.
// Oct (8 lanes) per edge: uint4 row gather -> 8 ds_add_f32.

#define AGG_SCATTER(W)                                                          \
    {                                                                           \
        uint4 u = *(const uint4*)(yr + (size_t)((W) & 0x1FFFF) * 64);           \
        float* a = &acc[((W) >> 17) * 65 + r * 8];                              \
        atomicAdd(a + 0, bflo(u.x)); atomicAdd(a + 1, bfraw(u.x));              \
        atomicAdd(a + 2, bflo(u.y)); atomicAdd(a + 3, bfraw(u.y));              \
        atomicAdd(a + 4, bflo(u.z)); atomicAdd(a + 5, bfraw(u.z));              \
        atomicAdd(a + 6, bflo(u.w)); atomicAdd(a + 7, bfraw(u.w));              \
    }

__global__ __launch_bounds__(256) void agg1s_k(const ushort* __restrict__ yh,
                                               const int* __restrict__ gbase,
                                               const uint* __restrict__ barr2,
                                               const float* __restrict__ bh,
                                               ushort* __restrict__ hh) {
    __shared__ float acc[129 * 65];
    int tid = threadIdx.x, blk = blockIdx.x;
    for (int i = tid; i < 129 * 65; i += 256) acc[i] = 0.f;
    __syncthreads();
    int s0 = gbase[blk], s1 = gbase[blk + 1];
    int wave = tid >> 6, lane = tid & 63, o = lane >> 3, r = lane & 7;
    const ushort* yr = yh + r * 8;

    for (int i = s0 + wave * 64; i < s1; i += 256) {
        int m = s1 - i; if (m > 64) m = 64;
        uint w = (lane < m) ? barr2[i + lane] : PADW;
#pragma unroll
        for (int g = 0; g < 2; ++g) {
            uint w0 = __shfl(w, g * 32 + o);
            uint w1 = __shfl(w, g * 32 + 8 + o);
            uint w2 = __shfl(w, g * 32 + 16 + o);
            uint w3 = __shfl(w, g * 32 + 24 + o);
            AGG_SCATTER(w0); AGG_SCATTER(w1); AGG_SCATTER(w2); AGG_SCATTER(w3);
        }
    }
    __syncthreads();

    int nodebase = blk * 128;
    for (int i = tid; i < 128 * 16; i += 256) {
        int nl = i >> 4, dg = i & 15;   // 4 dims per item
        int node = nodebase + nl;
        if (node < NN) {
            float a0 = acc[nl * 65 + dg * 4 + 0];
            float a1 = acc[nl * 65 + dg * 4 + 1];
            float a2 = acc[nl * 65 + dg * 4 + 2];
            float a3 = acc[nl * 65 + dg * 4 + 3];
            uint2 s = *(const uint2*)(yh + (size_t)node * 64 + dg * 4);
            float4 bb = *(const float4*)(bh + dg * 4);
            float v0 = fmaxf(a0 + bflo(s.x) + bb.x, 0.f);
            float v1 = fmaxf(a1 + bfhi(s.x) + bb.y, 0.f);
            float v2 = fmaxf(a2 + bflo(s.y) + bb.z, 0.f);
            float v3 = fmaxf(a3 + bfhi(s.y) + bb.w, 0.f);
            uint2 out;
            out.x = (uint)f2b(v0) | ((uint)f2b(v1) << 16);
            out.y = (uint)f2b(v2) | ((uint)f2b(v3) << 16);
            *(uint2*)(hh + (size_t)node * 64 + dg * 4) = out;
        }
    }
}

__global__ __launch_bounds__(256) void agg2s_k(const ushort* __restrict__ y2,
                                               const int* __restrict__ gbase,
                                               const uint* __restrict__ barr2,
                                               const float* __restrict__ b2,
                                               float* __restrict__ outp) {
    __shared__ float acc[129 * 65];
    int tid = threadIdx.x, blk = blockIdx.x;
    for (int i = tid; i < 129 * 65; i += 256) acc[i] = 0.f;
    __syncthreads();
    int s0 = gbase[blk], s1 = gbase[blk + 1];
    int wave = tid >> 6, lane = tid & 63, o = lane >> 3, r = lane & 7;
    const ushort* yr = y2 + r * 8;

    for (int i = s0 + wave * 64; i < s1; i += 256) {
        int m = s1 - i; if (m > 64) m = 64;
        uint w = (lane < m) ? barr2[i + lane] : PADW;
#pragma unroll
        for (int g = 0; g < 2; ++g) {
            uint w0 = __shfl(w, g * 32 + o);
            uint w1 = __shfl(w, g * 32 + 8 + o);
            uint w2 = __shfl(w, g * 32 + 16 + o);
            uint w3 = __shfl(w, g * 32 + 24 + o);
            AGG_SCATTER(w0); AGG_SCATTER(w1); AGG_SCATTER(w2); AGG_SCATTER(w3);
        }
    }
    __syncthreads();

    int nodebase = blk * 128;
    for (int i = tid; i < 128 * 16; i += 256) {
        int nl = i >> 4, dg = i & 15;
        int node = nodebase + nl;
        if (node < NN) {
            float a0 = acc[nl * 65 + dg * 4 + 0];
            float a1 = acc[nl * 65 + dg * 4 + 1];
            float a2 = acc[nl * 65 + dg * 4 + 2];
            float a3 = acc[nl * 65 + dg * 4 + 3];
            uint2 s = *(const uint2*)(y2 + (size_t)node * 64 + dg * 4);
            float4 bb = *(const float4*)(b2 + dg * 4);
            float4 ov;
            ov.x = a0 + bflo(s.x) + bb.x;
            ov.y = a1 + bfhi(s.x) + bb.y;
            ov.z = a2 + bflo(s.y) + bb.z;
            ov.w = a3 + bfhi(s.y) + bb.w;
            *(float4*)(outp + (size_t)node * 64 + dg * 4) = ov;
        }
    }
}

// ---------------- launch ----------------

static constexpr size_t alup(size_t x) { return (x + 255) & ~(size_t)255; }
static constexpr size_t OFF_HIST  = 0;
static constexpr size_t OFF_PBASE = alup(OFF_HIST  + (size_t)NB * NBK * 4);
static constexpr size_t OFF_TOT   = alup(OFF_PBASE + (size_t)NB * NBK * 4);
static constexpr size_t OFF_GBASE = alup(OFF_TOT   + NBK * 4);
static constexpr size_t OFF_BARR  = alup(OFF_GBASE + (NBK + 1) * 4);
static constexpr size_t OFF_BARR2 = alup(OFF_BARR  + (size_t)NE * 4);
static constexpr size_t OFF_Y1A   = alup(OFF_BARR2 + (size_t)NE * 4);
static constexpr size_t OFF_Y1B   = alup(OFF_Y1A + (size_t)(NN + 1) * 64 * 2);
static constexpr size_t OFF_HA    = alup(OFF_Y1B + (size_t)(NN + 1) * 64 * 2);
static constexpr size_t OFF_HB    = alup(OFF_HA  + (size_t)(NN + 1) * 64 * 2);
static constexpr size_t OFF_Y2    = alup(OFF_HB  + (size_t)(NN + 1) * 64 * 2);

extern "C" void kernel_launch(void* const* d_in, const int* in_sizes, int n_in,
                              void* d_out, int out_size, void* d_ws, size_t ws_size,
                              hipStream_t stream) {
    const float* x  = (const float*)d_in[0];
    const int*   ei = (const int*)d_in[1];
    const float* W1 = (const float*)d_in[2];
    const float* b1 = (const float*)d_in[3];
    const float* W2 = (const float*)d_in[4];
    const float* b2 = (const float*)d_in[5];
    float* out = (float*)d_out;
    char* ws = (char*)d_ws;

    int*  hist  = (int*)(ws + OFF_HIST);
    int*  pbase = (int*)(ws + OFF_PBASE);
    int*  tot   = (int*)(ws + OFF_TOT);
    int*  gbase = (int*)(ws + OFF_GBASE);
    uint* barr  = (uint*)(ws + OFF_BARR);
    uint* barr2 = (uint*)(ws + OFF_BARR2);
    ushort* y1a = (ushort*)(ws + OFF_Y1A);
    ushort* y1b = (ushort*)(ws + OFF_Y1B);
    ushort* ha  = (ushort*)(ws + OFF_HA);
    ushort* hb  = (ushort*)(ws + OFF_HB);
    ushort* y2  = (ushort*)(ws + OFF_Y2);

    hipLaunchKernelGGL(hist2_k,  dim3(NB),  dim3(512),  0, stream, ei, hist);
    hipLaunchKernelGGL(pbase_k,  dim3(NBK), dim3(64),   0, stream, hist, pbase, tot);
    hipLaunchKernelGGL(bscan_k,  dim3(1),   dim3(1024), 0, stream, tot, gbase, y1a, y1b, y2);
    hipLaunchKernelGGL(bfill2_k, dim3(NB),  dim3(512),  0, stream, ei, pbase, gbase, barr);
    hipLaunchKernelGGL(sort_k,   dim3(NBK), dim3(256),  0, stream, barr, gbase, barr2);

    hipLaunchKernelGGL(gemm1_k, dim3(782), dim3(256), 0, stream, x, W1, y1a, y1b);
    hipLaunchKernelGGL(agg1s_k, dim3(NBK), dim3(256), 0, stream, y1a, gbase, barr2, b1,      ha);
    hipLaunchKernelGGL(agg1s_k, dim3(NBK), dim3(256), 0, stream, y1b, gbase, barr2, b1 + 64, hb);
    hipLaunchKernelGGL(gemm2_k, dim3(782), dim3(256), 0, stream, ha, hb, W2, y2);
    hipLaunchKernelGGL(agg2s_k, dim3(NBK), dim3(256), 0, stream, y2, gbase, barr2, b2, out);
}

// Round 11
// 241.819 us; speedup vs baseline: 17.1515x; 17.1515x over previous
//
#include <hip/hip_runtime.h>
#include <stdint.h>

#define NN 100000
#define NE 3200000
#define NBK 391          // ceil(NN/256) buckets of 256 dst nodes
#define NB  256          // sort blocks
#define CH  12500        // edges per sort block: 256*12500 = 3.2M = NE
#define CSRCAP 8960      // LDS staging capacity per bucket (mean 8184, sigma ~90)

typedef unsigned int uint;
typedef unsigned short ushort;
typedef __attribute__((ext_vector_type(8))) short bf16x8;
typedef __attribute__((ext_vector_type(4))) float f32x4;

static __device__ __forceinline__ float bflo(uint v) {
    uint u = v << 16; return __builtin_bit_cast(float, u);
}
static __device__ __forceinline__ float bfhi(uint v) {
    uint u = v & 0xffff0000u; return __builtin_bit_cast(float, u);
}
static __device__ __forceinline__ float bfraw(uint v) {   // hi bf16 with low-bit junk (<=2^-9 rel)
    return __builtin_bit_cast(float, v);
}
static __device__ __forceinline__ ushort f2b(float f) {  // RNE fp32->bf16
    uint u = __builtin_bit_cast(uint, f);
    u += 0x7fffu + ((u >> 16) & 1u);
    return (ushort)(u >> 16);
}
static __device__ __forceinline__ int wscan(int v, int lane) {  // 64-lane inclusive
#pragma unroll
    for (int off = 1; off < 64; off <<= 1) {
        int t = __shfl_up(v, off);
        if (lane >= off) v += t;
    }
    return v;
}

// ---------------- deterministic bucket counting-sort ----------------

// int4-vectorized per-block histogram (CH = 4*3125, chunks 16B-aligned).
__global__ __launch_bounds__(512) void hist2_k(const int* __restrict__ ei,
                                               int* __restrict__ hist) {
    __shared__ int hl[NBK];
    int tid = threadIdx.x, b = blockIdx.x;
    for (int k = tid; k < NBK; k += 512) hl[k] = 0;
    __syncthreads();
    const int4* dst4 = (const int4*)(ei + NE + b * CH);
    for (int i = tid; i < CH / 4; i += 512) {
        int4 d = dst4[i];
        atomicAdd(&hl[d.x >> 8], 1);
        atomicAdd(&hl[d.y >> 8], 1);
        atomicAdd(&hl[d.z >> 8], 1);
        atomicAdd(&hl[d.w >> 8], 1);
    }
    __syncthreads();
    for (int k = tid; k < NBK; k += 512) hist[b * NBK + k] = hl[k];
}

__global__ __launch_bounds__(64) void pbase_k(const int* __restrict__ hist,
                                              int* __restrict__ pbase,
                                              int* __restrict__ totals) {
    int k = blockIdx.x, lane = threadIdx.x;
    int carry = 0;
#pragma unroll
    for (int c = 0; c < NB / 64; ++c) {
        int b = c * 64 + lane;
        int v = hist[b * NBK + k];
        int incl = wscan(v, lane);
        pbase[b * NBK + k] = carry + incl - v;
        carry += __shfl(incl, 63);
    }
    if (lane == 0) totals[k] = carry;
}

// scan bucket totals -> gbase; also zero the pad rows (index NN) of y1a/y1b/y2.
__global__ __launch_bounds__(1024) void bscan_k(const int* __restrict__ totals,
                                                int* __restrict__ gbase,
                                                int* __restrict__ nodeptr,
                                                ushort* __restrict__ y1a,
                                                ushort* __restrict__ y1b,
                                                ushort* __restrict__ y2) {
    __shared__ int sd[1024];
    int t = threadIdx.x;
    int v = (t < NBK) ? totals[t] : 0;
    sd[t] = v;
    __syncthreads();
    for (int off = 1; off < 1024; off <<= 1) {
        int u = (t >= off) ? sd[t - off] : 0;
        __syncthreads();
        sd[t] += u;
        __syncthreads();
    }
    int excl = sd[t] - v;
    if (t < NBK) gbase[t] = excl;
    if (t == 0) { gbase[NBK] = NE; nodeptr[NN] = NE; }
    if (t < 32)              ((uint*)(y1a + (size_t)NN * 64))[t] = 0;
    else if (t < 64)         ((uint*)(y1b + (size_t)NN * 64))[t - 32] = 0;
    else if (t < 96)         ((uint*)(y2  + (size_t)NN * 64))[t - 64] = 0;
}

// direct scatter with LDS cursors seeded from gbase+pbase; int4 edge loads.
__global__ __launch_bounds__(512) void bfill2_k(const int* __restrict__ ei,
                                                const int* __restrict__ pbase,
                                                const int* __restrict__ gbase,
                                                uint* __restrict__ barr) {
    __shared__ int cur[NBK];
    int tid = threadIdx.x, b = blockIdx.x;
    for (int k = tid; k < NBK; k += 512)
        cur[k] = gbase[k] + pbase[b * NBK + k];
    __syncthreads();
    const int4* src4 = (const int4*)(ei + b * CH);
    const int4* dst4 = (const int4*)(ei + NE + b * CH);
    for (int i = tid; i < CH / 4; i += 512) {
        int4 s = src4[i];
        int4 d = dst4[i];
        int p0 = atomicAdd(&cur[d.x >> 8], 1);
        barr[p0] = ((uint)(d.x & 255) << 17) | (uint)s.x;
        int p1 = atomicAdd(&cur[d.y >> 8], 1);
        barr[p1] = ((uint)(d.y & 255) << 17) | (uint)s.y;
        int p2 = atomicAdd(&cur[d.z >> 8], 1);
        barr[p2] = ((uint)(d.z & 255) << 17) | (uint)s.z;
        int p3 = atomicAdd(&cur[d.w >> 8], 1);
        barr[p3] = ((uint)(d.w & 255) << 17) | (uint)s.w;
    }
}

// within-bucket counting sort via LDS staging (single global read of the bucket).
__global__ __launch_bounds__(256) void csr_k(const uint* __restrict__ barr,
                                             const int* __restrict__ gbase,
                                             int* __restrict__ nodeptr,
                                             uint* __restrict__ col) {
    __shared__ uint stg[CSRCAP];
    __shared__ int cnt[256], cur[256];
    int tid = threadIdx.x;
    int blk = blockIdx.x;
    int s0 = gbase[blk], s1 = gbase[blk + 1];
    int n = s1 - s0;
    bool fits = (n <= CSRCAP);
    cnt[tid] = 0;
    __syncthreads();
    if (fits) {
        for (int i = tid; i < n; i += 256) {
            uint e = barr[s0 + i];
            stg[i] = e;
            atomicAdd(&cnt[e >> 17], 1);
        }
    } else {
        for (int i = s0 + tid; i < s1; i += 256)
            atomicAdd(&cnt[barr[i] >> 17], 1);
    }
    __syncthreads();
    if (tid < 64) {
        int c0 = cnt[4 * tid], c1 = cnt[4 * tid + 1];
        int c2 = cnt[4 * tid + 2], c3 = cnt[4 * tid + 3];
        int s = c0 + c1 + c2 + c3;
        int incl = wscan(s, tid);
        int excl = incl - s;
        cur[4 * tid]     = excl;
        cur[4 * tid + 1] = excl + c0;
        cur[4 * tid + 2] = excl + c0 + c1;
        cur[4 * tid + 3] = excl + c0 + c1 + c2;
        int node = blk * 256 + 4 * tid;
        if (node < NN)     nodeptr[node]     = s0 + excl;
        if (node + 1 < NN) nodeptr[node + 1] = s0 + excl + c0;
        if (node + 2 < NN) nodeptr[node + 2] = s0 + excl + c0 + c1;
        if (node + 3 < NN) nodeptr[node + 3] = s0 + excl + c0 + c1 + c2;
    }
    __syncthreads();
    if (fits) {
        for (int i = tid; i < n; i += 256) {
            uint e = stg[i];
            int pos = s0 + atomicAdd(&cur[e >> 17], 1);
            col[pos] = e & 0x1FFFF;
        }
    } else {
        for (int i = s0 + tid; i < s1; i += 256) {
            uint e = barr[i];
            int pos = s0 + atomicAdd(&cur[e >> 17], 1);
            col[pos] = e & 0x1FFFF;
        }
    }
}

// ---------------- GEMM1: y1 = bf16( x @ W1^T ), planar halves ----------------
__global__ __launch_bounds__(256) void gemm1_k(const float* __restrict__ x,
                                               const float* __restrict__ W1,
                                               ushort* __restrict__ y1a,
                                               ushort* __restrict__ y1b) {
    __shared__ ushort wl[128 * 136];
    int tid = threadIdx.x;
    for (int i = tid; i < 128 * 128; i += 256)
        wl[(i >> 7) * 136 + (i & 127)] = f2b(W1[i]);
    __syncthreads();

    int wave = tid >> 6, lane = tid & 63;
    int lr = lane & 15, lk = (lane >> 4) * 8;
    long rowbase = (long)blockIdx.x * 128 + wave * 32;

    f32x4 acc[2][8] = {};
    for (int kc = 0; kc < 128; kc += 32) {
        bf16x8 a[2];
#pragma unroll
        for (int m = 0; m < 2; m++) {
            long row = rowbase + m * 16 + lr;
            if (row > NN - 1) row = NN - 1;
            const float* p = x + row * 128 + kc + lk;
            float f[8];
            *(float4*)(f)     = *(const float4*)(p);
            *(float4*)(f + 4) = *(const float4*)(p + 4);
            bf16x8 t;
#pragma unroll
            for (int j = 0; j < 8; j++) t[j] = (short)f2b(f[j]);
            a[m] = t;
        }
#pragma unroll
        for (int nb = 0; nb < 8; nb++) {
            bf16x8 b = *(const bf16x8*)&wl[(nb * 16 + lr) * 136 + kc + lk];
            acc[0][nb] = __builtin_amdgcn_mfma_f32_16x16x32_bf16(a[0], b, acc[0][nb], 0, 0, 0);
            acc[1][nb] = __builtin_amdgcn_mfma_f32_16x16x32_bf16(a[1], b, acc[1][nb], 0, 0, 0);
        }
    }
    int rq = (lane >> 4) * 4;
#pragma unroll
    for (int m = 0; m < 2; m++) {
#pragma unroll
        for (int r = 0; r < 4; r++) {
            long row = rowbase + m * 16 + rq + r;
            if (row < NN) {
#pragma unroll
                for (int nb = 0; nb < 8; nb++) {
                    ushort v = f2b(acc[m][nb][r]);
                    if (nb < 4) y1a[row * 64 + nb * 16 + lr] = v;
                    else        y1b[row * 64 + (nb - 4) * 16 + lr] = v;
                }
            }
        }
    }
}

// ---------------- GEMM2: y2 = bf16( h @ W2^T ), h in planar halves ----------------
__global__ __launch_bounds__(256) void gemm2_k(const ushort* __restrict__ ha,
                                               const ushort* __restrict__ hb,
                                               const float* __restrict__ W2,
                                               ushort* __restrict__ y2) {
    __shared__ ushort wl[64 * 136];
    int tid = threadIdx.x;
    for (int i = tid; i < 64 * 128; i += 256)
        wl[(i >> 7) * 136 + (i & 127)] = f2b(W2[i]);
    __syncthreads();

    int wave = tid >> 6, lane = tid & 63;
    int lr = lane & 15, lk = (lane >> 4) * 8;
    long rowbase = (long)blockIdx.x * 128 + wave * 32;

    f32x4 acc[2][4] = {};
#pragma unroll
    for (int kc = 0; kc < 128; kc += 32) {
        const ushort* hsrc = (kc < 64) ? ha : hb;
        int koff = kc & 63;
        bf16x8 a[2];
#pragma unroll
        for (int m = 0; m < 2; m++) {
            long row = rowbase + m * 16 + lr;
            if (row > NN - 1) row = NN - 1;
            a[m] = *(const bf16x8*)(hsrc + row * 64 + koff + lk);
        }
#pragma unroll
        for (int nb = 0; nb < 4; nb++) {
            bf16x8 b = *(const bf16x8*)&wl[(nb * 16 + lr) * 136 + kc + lk];
            acc[0][nb] = __builtin_amdgcn_mfma_f32_16x16x32_bf16(a[0], b, acc[0][nb], 0, 0, 0);
            acc[1][nb] = __builtin_amdgcn_mfma_f32_16x16x32_bf16(a[1], b, acc[1][nb], 0, 0, 0);
        }
    }
    int rq = (lane >> 4) * 4;
#pragma unroll
    for (int m = 0; m < 2; m++) {
#pragma unroll
        for (int r = 0; r < 4; r++) {
            long row = rowbase + m * 16 + rq + r;
            if (row < NN) {
#pragma unroll
                for (int nb = 0; nb < 4; nb++)
                    y2[row * 64 + nb * 16 + lr] = f2b(acc[m][nb][r]);
            }
        }
    }
}

// ---------------- pull aggregation: wave per node, OCT (8 lanes) per edge ----------------

__global__ __launch_bounds__(256) void agg1h_k(const ushort* __restrict__ yh,
                                               const int* __restrict__ nodeptr,
                                               const uint* __restrict__ col,
                                               const float* __restrict__ bh,
                                               ushort* __restrict__ hh) {
    int wid = (blockIdx.x * 256 + threadIdx.x) >> 6;
    int lane = threadIdx.x & 63;
    if (wid >= NN) return;
    int s0 = nodeptr[wid], s1 = nodeptr[wid + 1];
    int o = lane >> 3, r = lane & 7;

    float aLo[4] = {}, aHi[4] = {};
    const ushort* yr = yh + r * 8;

    for (int i = s0; i < s1; i += 64) {
        int m = s1 - i; if (m > 64) m = 64;
        int sv = (lane < m) ? (int)col[i + lane] : NN;
        int jg = (m + 31) >> 5;                    // groups of 32 edges
        for (int g = 0; g < jg; ++g) {
            int e0 = 32 * g + o;
            int sj0 = __shfl(sv, e0);
            int sj1 = __shfl(sv, e0 + 8);
            int sj2 = __shfl(sv, e0 + 16);
            int sj3 = __shfl(sv, e0 + 24);
            uint4 u0 = *(const uint4*)(yr + (size_t)sj0 * 64);
            uint4 u1 = *(const uint4*)(yr + (size_t)sj1 * 64);
            uint4 u2 = *(const uint4*)(yr + (size_t)sj2 * 64);
            uint4 u3 = *(const uint4*)(yr + (size_t)sj3 * 64);
            aLo[0] += bflo(u0.x); aHi[0] += bfraw(u0.x);
            aLo[1] += bflo(u0.y); aHi[1] += bfraw(u0.y);
            aLo[2] += bflo(u0.z); aHi[2] += bfraw(u0.z);
            aLo[3] += bflo(u0.w); aHi[3] += bfraw(u0.w);
            aLo[0] += bflo(u1.x); aHi[0] += bfraw(u1.x);
            aLo[1] += bflo(u1.y); aHi[1] += bfraw(u1.y);
            aLo[2] += bflo(u1.z); aHi[2] += bfraw(u1.z);
            aLo[3] += bflo(u1.w); aHi[3] += bfraw(u1.w);
            aLo[0] += bflo(u2.x); aHi[0] += bfraw(u2.x);
            aLo[1] += bflo(u2.y); aHi[1] += bfraw(u2.y);
            aLo[2] += bflo(u2.z); aHi[2] += bfraw(u2.z);
            aLo[3] += bflo(u2.w); aHi[3] += bfraw(u2.w);
            aLo[0] += bflo(u3.x); aHi[0] += bfraw(u3.x);
            aLo[1] += bflo(u3.y); aHi[1] += bfraw(u3.y);
            aLo[2] += bflo(u3.z); aHi[2] += bfraw(u3.z);
            aLo[3] += bflo(u3.w); aHi[3] += bfraw(u3.w);
        }
    }
#pragma unroll
    for (int d = 0; d < 4; ++d) {
        aLo[d] += __shfl_xor(aLo[d], 8);  aHi[d] += __shfl_xor(aHi[d], 8);
        aLo[d] += __shfl_xor(aLo[d], 16); aHi[d] += __shfl_xor(aHi[d], 16);
        aLo[d] += __shfl_xor(aLo[d], 32); aHi[d] += __shfl_xor(aHi[d], 32);
    }
    if (o == 0) {
        uint4 s = *(const uint4*)(yh + (size_t)wid * 64 + r * 8);
        float4 bA = *(const float4*)(bh + r * 8);
        float4 bB = *(const float4*)(bh + r * 8 + 4);
        float v0 = fmaxf(aLo[0] + bflo(s.x) + bA.x, 0.f);
        float v1 = fmaxf(aHi[0] + bfhi(s.x) + bA.y, 0.f);
        float v2 = fmaxf(aLo[1] + bflo(s.y) + bA.z, 0.f);
        float v3 = fmaxf(aHi[1] + bfhi(s.y) + bA.w, 0.f);
        float v4 = fmaxf(aLo[2] + bflo(s.z) + bB.x, 0.f);
        float v5 = fmaxf(aHi[2] + bfhi(s.z) + bB.y, 0.f);
        float v6 = fmaxf(aLo[3] + bflo(s.w) + bB.z, 0.f);
        float v7 = fmaxf(aHi[3] + bfhi(s.w) + bB.w, 0.f);
        uint4 out;
        out.x = (uint)f2b(v0) | ((uint)f2b(v1) << 16);
        out.y = (uint)f2b(v2) | ((uint)f2b(v3) << 16);
        out.z = (uint)f2b(v4) | ((uint)f2b(v5) << 16);
        out.w = (uint)f2b(v6) | ((uint)f2b(v7) << 16);
        *(uint4*)(hh + (size_t)wid * 64 + r * 8) = out;
    }
}

__global__ __launch_bounds__(256) void agg2_k(const ushort* __restrict__ y2,
                                              const int* __restrict__ nodeptr,
                                              const uint* __restrict__ col,
                                              const float* __restrict__ b2,
                                              float* __restrict__ out) {
    int wid = (blockIdx.x * 256 + threadIdx.x) >> 6;
    int lane = threadIdx.x & 63;
    if (wid >= NN) return;
    int s0 = nodeptr[wid], s1 = nodeptr[wid + 1];
    int o = lane >> 3, r = lane & 7;

    float aLo[4] = {}, aHi[4] = {};
    const ushort* yr = y2 + r * 8;

    for (int i = s0; i < s1; i += 64) {
        int m = s1 - i; if (m > 64) m = 64;
        int sv = (lane < m) ? (int)col[i + lane] : NN;
        int jg = (m + 31) >> 5;
        for (int g = 0; g < jg; ++g) {
            int e0 = 32 * g + o;
            int sj0 = __shfl(sv, e0);
            int sj1 = __shfl(sv, e0 + 8);
            int sj2 = __shfl(sv, e0 + 16);
            int sj3 = __shfl(sv, e0 + 24);
            uint4 u0 = *(const uint4*)(yr + (size_t)sj0 * 64);
            uint4 u1 = *(const uint4*)(yr + (size_t)sj1 * 64);
            uint4 u2 = *(const uint4*)(yr + (size_t)sj2 * 64);
            uint4 u3 = *(const uint4*)(yr + (size_t)sj3 * 64);
            aLo[0] += bflo(u0.x); aHi[0] += bfraw(u0.x);
            aLo[1] += bflo(u0.y); aHi[1] += bfraw(u0.y);
            aLo[2] += bflo(u0.z); aHi[2] += bfraw(u0.z);
            aLo[3] += bflo(u0.w); aHi[3] += bfraw(u0.w);
            aLo[0] += bflo(u1.x); aHi[0] += bfraw(u1.x);
            aLo[1] += bflo(u1.y); aHi[1] += bfraw(u1.y);
            aLo[2] += bflo(u1.z); aHi[2] += bfraw(u1.z);
            aLo[3] += bflo(u1.w); aHi[3] += bfraw(u1.w);
            aLo[0] += bflo(u2.x); aHi[0] += bfraw(u2.x);
            aLo[1] += bflo(u2.y); aHi[1] += bfraw(u2.y);
            aLo[2] += bflo(u2.z); aHi[2] += bfraw(u2.z);
            aLo[3] += bflo(u2.w); aHi[3] += bfraw(u2.w);
            aLo[0] += bflo(u3.x); aHi[0] += bfraw(u3.x);
            aLo[1] += bflo(u3.y); aHi[1] += bfraw(u3.y);
            aLo[2] += bflo(u3.z); aHi[2] += bfraw(u3.z);
            aLo[3] += bflo(u3.w); aHi[3] += bfraw(u3.w);
        }
    }
#pragma unroll
    for (int d = 0; d < 4; ++d) {
        aLo[d] += __shfl_xor(aLo[d], 8);  aHi[d] += __shfl_xor(aHi[d], 8);
        aLo[d] += __shfl_xor(aLo[d], 16); aHi[d] += __shfl_xor(aHi[d], 16);
        aLo[d] += __shfl_xor(aLo[d], 32); aHi[d] += __shfl_xor(aHi[d], 32);
    }
    if (o == 0) {
        uint4 s = *(const uint4*)(y2 + (size_t)wid * 64 + r * 8);
        float4 bA = *(const float4*)(b2 + r * 8);
        float4 bB = *(const float4*)(b2 + r * 8 + 4);
        float4 o0, o1;
        o0.x = aLo[0] + bflo(s.x) + bA.x;
        o0.y = aHi[0] + bfhi(s.x) + bA.y;
        o0.z = aLo[1] + bflo(s.y) + bA.z;
        o0.w = aHi[1] + bfhi(s.y) + bA.w;
        o1.x = aLo[2] + bflo(s.z) + bB.x;
        o1.y = aHi[2] + bfhi(s.z) + bB.y;
        o1.z = aLo[3] + bflo(s.w) + bB.z;
        o1.w = aHi[3] + bfhi(s.w) + bB.w;
        *(float4*)(out + (size_t)wid * 64 + r * 8)     = o0;
        *(float4*)(out + (size_t)wid * 64 + r * 8 + 4) = o1;
    }
}

// ---------------- launch ----------------

static constexpr size_t alup(size_t x) { return (x + 255) & ~(size_t)255; }
static constexpr size_t OFF_HIST  = 0;
static constexpr size_t OFF_PBASE = alup(OFF_HIST  + (size_t)NB * NBK * 4);
static constexpr size_t OFF_TOT   = alup(OFF_PBASE + (size_t)NB * NBK * 4);
static constexpr size_t OFF_GBASE = alup(OFF_TOT   + NBK * 4);
static constexpr size_t OFF_NPTR  = alup(OFF_GBASE + (NBK + 1) * 4);
static constexpr size_t OFF_BARR  = alup(OFF_NPTR  + (size_t)(NN + 1) * 4);
static constexpr size_t OFF_COL   = alup(OFF_BARR  + (size_t)NE * 4);
static constexpr size_t OFF_Y1A   = alup(OFF_COL   + (size_t)NE * 4);
static constexpr size_t OFF_Y1B   = alup(OFF_Y1A + (size_t)(NN + 1) * 64 * 2);
static constexpr size_t OFF_HA    = alup(OFF_Y1B + (size_t)(NN + 1) * 64 * 2);
static constexpr size_t OFF_HB    = alup(OFF_HA  + (size_t)(NN + 1) * 64 * 2);
static constexpr size_t OFF_Y2    = alup(OFF_HB  + (size_t)(NN + 1) * 64 * 2);

extern "C" void kernel_launch(void* const* d_in, const int* in_sizes, int n_in,
                              void* d_out, int out_size, void* d_ws, size_t ws_size,
                              hipStream_t stream) {
    const float* x  = (const float*)d_in[0];
    const int*   ei = (const int*)d_in[1];
    const float* W1 = (const float*)d_in[2];
    const float* b1 = (const float*)d_in[3];
    const float* W2 = (const float*)d_in[4];
    const float* b2 = (const float*)d_in[5];
    float* out = (float*)d_out;
    char* ws = (char*)d_ws;

    int*  hist  = (int*)(ws + OFF_HIST);
    int*  pbase = (int*)(ws + OFF_PBASE);
    int*  tot   = (int*)(ws + OFF_TOT);
    int*  gbase = (int*)(ws + OFF_GBASE);
    int*  nptr  = (int*)(ws + OFF_NPTR);
    uint* barr  = (uint*)(ws + OFF_BARR);
    uint* colA  = (uint*)(ws + OFF_COL);
    ushort* y1a = (ushort*)(ws + OFF_Y1A);
    ushort* y1b = (ushort*)(ws + OFF_Y1B);
    ushort* ha  = (ushort*)(ws + OFF_HA);
    ushort* hb  = (ushort*)(ws + OFF_HB);
    ushort* y2  = (ushort*)(ws + OFF_Y2);

    hipLaunchKernelGGL(hist2_k,  dim3(NB),  dim3(512),  0, stream, ei, hist);
    hipLaunchKernelGGL(pbase_k,  dim3(NBK), dim3(64),   0, stream, hist, pbase, tot);
    hipLaunchKernelGGL(bscan_k,  dim3(1),   dim3(1024), 0, stream, tot, gbase, nptr, y1a, y1b, y2);
    hipLaunchKernelGGL(bfill2_k, dim3(NB),  dim3(512),  0, stream, ei, pbase, gbase, barr);
    hipLaunchKernelGGL(csr_k,    dim3(NBK), dim3(256),  0, stream, barr, gbase, nptr, colA);

    hipLaunchKernelGGL(gemm1_k, dim3(782),  dim3(256), 0, stream, x, W1, y1a, y1b);
    hipLaunchKernelGGL(agg1h_k, dim3(25000),dim3(256), 0, stream, y1a, nptr, colA, b1,      ha);
    hipLaunchKernelGGL(agg1h_k, dim3(25000),dim3(256), 0, stream, y1b, nptr, colA, b1 + 64, hb);
    hipLaunchKernelGGL(gemm2_k, dim3(782),  dim3(256), 0, stream, ha, hb, W2, y2);
    hipLaunchKernelGGL(agg2_k,  dim3(25000),dim3(256), 0, stream, y2, nptr, colA, b2, out);
}